// Round 19
// baseline (266.869 us; speedup 1.0000x reference)
//
#include <hip/hip_runtime.h>
#include <cstdint>
#include <cmath>

typedef unsigned short u16;
typedef __bf16 bf16_t;
typedef bf16_t bf16x8 __attribute__((ext_vector_type(8)));
typedef float f32x4 __attribute__((ext_vector_type(4)));
typedef u16 u16x8 __attribute__((ext_vector_type(8)));
typedef u16 u16x4 __attribute__((ext_vector_type(4)));

#define DEV __device__ __forceinline__

DEV u16 f2b(float f) {
    uint32_t u = __builtin_bit_cast(uint32_t, f);
    u += 0x7FFFu + ((u >> 16) & 1u);
    return (u16)(u >> 16);
}
DEV float b2f(u16 h) { return __builtin_bit_cast(float, (uint32_t)h << 16); }

DEV bf16x8 load8(const u16* p) {
    return __builtin_bit_cast(bf16x8, *reinterpret_cast<const u16x8*>(p));
}

DEV void async16(void* lds, const void* g) {
    __builtin_amdgcn_global_load_lds(
        reinterpret_cast<const __attribute__((address_space(1))) void*>(
            reinterpret_cast<uintptr_t>(g)),
        reinterpret_cast<__attribute__((address_space(3))) void*>(
            reinterpret_cast<uintptr_t>(lds)),
        16, 0, 0);
}

DEV float gelu_t(float x) {
    float z = 0.7978845608028654f * (x + 0.044715f * x * x * x);
    z = fminf(fmaxf(z, -15.0f), 15.0f);
    float e = __expf(2.0f * z);
    return 0.5f * x * (1.0f + (e - 1.0f) / (e + 1.0f));
}

// ------- prep: all 4 weight transposes (blocks 0..6911) + ln1 (blocks 6912..8959) -----
__global__ __launch_bounds__(256) void prep_k(const float* __restrict__ w0,
                                              const float* __restrict__ w1,
                                              const float* __restrict__ w2,
                                              const float* __restrict__ w3,
                                              u16* __restrict__ o0, u16* __restrict__ o1,
                                              u16* __restrict__ o2, u16* __restrict__ o3,
                                              const float* __restrict__ x,
                                              const float* __restrict__ g,
                                              const float* __restrict__ bb,
                                              u16* __restrict__ h) {
    __shared__ float tile[32][33];
    const int id = blockIdx.x;
    const int tx = threadIdx.x, ty = threadIdx.y;
    if (id < 6912) {
        const float* W;
        u16* WT;
        int K, N, loc;
        if (id < 1728) {
            W = w0; WT = o0; K = 768; N = 2304; loc = id;
        } else if (id < 2304) {
            W = w1; WT = o1; K = 768; N = 768; loc = id - 1728;
        } else if (id < 4608) {
            W = w2; WT = o2; K = 768; N = 3072; loc = id - 2304;
        } else {
            W = w3; WT = o3; K = 3072; N = 768; loc = id - 4608;
        }
        const int nx = N >> 5;
        const int n0 = (loc % nx) * 32, k0 = (loc / nx) * 32;
#pragma unroll
        for (int i = 0; i < 4; ++i)
            tile[ty + i * 8][tx] = W[(size_t)(k0 + ty + i * 8) * N + n0 + tx];
        __syncthreads();
#pragma unroll
        for (int i = 0; i < 4; ++i)
            WT[(size_t)(n0 + ty + i * 8) * K + k0 + tx] = f2b(tile[tx][ty + i * 8]);
    } else {
        const int flat = ty * 32 + tx;
        const int lane = flat & 63, w = flat >> 6;
        const int row = (id - 6912) * 4 + w;
        const float4* xr = reinterpret_cast<const float4*>(x + (size_t)row * 768);
        float4 v[3];
        float s = 0.f, s2 = 0.f;
#pragma unroll
        for (int i = 0; i < 3; ++i) {
            v[i] = xr[i * 64 + lane];
            s += v[i].x + v[i].y + v[i].z + v[i].w;
            s2 += v[i].x * v[i].x + v[i].y * v[i].y + v[i].z * v[i].z + v[i].w * v[i].w;
        }
#pragma unroll
        for (int off = 1; off < 64; off <<= 1) {
            s += __shfl_xor(s, off);
            s2 += __shfl_xor(s2, off);
        }
        const float mu = s * (1.0f / 768.0f);
        const float rstd = rsqrtf(s2 * (1.0f / 768.0f) - mu * mu + 1e-5f);
#pragma unroll
        for (int i = 0; i < 3; ++i) {
            int col = i * 256 + lane * 4;
            u16x4 o;
            o[0] = f2b((v[i].x - mu) * rstd * g[col + 0] + bb[col + 0]);
            o[1] = f2b((v[i].y - mu) * rstd * g[col + 1] + bb[col + 1]);
            o[2] = f2b((v[i].z - mu) * rstd * g[col + 2] + bb[col + 2]);
            o[3] = f2b((v[i].w - mu) * rstd * g[col + 3] + bb[col + 3]);
            *reinterpret_cast<u16x4*>(h + (size_t)row * 768 + col) = o;
        }
    }
}

// ---------------- LayerNorm bf16-in: 1 wave per row of 768 -> bf16 ----------------
__global__ __launch_bounds__(256) void ln_b16(const u16* __restrict__ x,
                                              const float* __restrict__ g,
                                              const float* __restrict__ bb,
                                              u16* __restrict__ out) {
    const int lane = threadIdx.x & 63, w = threadIdx.x >> 6;
    const int row = blockIdx.x * 4 + w;
    const u16* xr = x + (size_t)row * 768;
    float v[12];
    float s = 0.f, s2 = 0.f;
#pragma unroll
    for (int i = 0; i < 3; ++i) {
        u16x4 u = *reinterpret_cast<const u16x4*>(xr + i * 256 + lane * 4);
#pragma unroll
        for (int jj = 0; jj < 4; ++jj) {
            float f = b2f(u[jj]);
            v[i * 4 + jj] = f;
            s += f;
            s2 += f * f;
        }
    }
#pragma unroll
    for (int off = 1; off < 64; off <<= 1) {
        s += __shfl_xor(s, off);
        s2 += __shfl_xor(s2, off);
    }
    const float mu = s * (1.0f / 768.0f);
    const float rstd = rsqrtf(s2 * (1.0f / 768.0f) - mu * mu + 1e-5f);
#pragma unroll
    for (int i = 0; i < 3; ++i) {
        int col = i * 256 + lane * 4;
        u16x4 o;
#pragma unroll
        for (int jj = 0; jj < 4; ++jj)
            o[jj] = f2b((v[i * 4 + jj] - mu) * rstd * g[col + jj] + bb[col + jj]);
        *reinterpret_cast<u16x4*>(out + (size_t)row * 768 + col) = o;
    }
}

// ------------- GEMM 128x256 "wide": BK=32, 4 waves (2Mx2N), each wave 64x128 ---------
// 2x FLOPs per LDS byte vs 128x128 (the measured saturated pipe): 24KB staged + 48
// ds_read_b128 per 128 block-MFMA. 3-slot rotation (72KB -> 2 blocks/CU), 1 barrier
// per K-step, literal slots, vmcnt(6). For machine-filling grids (qkv 576, fc1 768).
template <int ACT, int MFAST, int VOUT>
__global__ __launch_bounds__(256) void gemm_wide(const u16* __restrict__ A,
                                                 const u16* __restrict__ BT,
                                                 const float* __restrict__ bias,
                                                 u16* __restrict__ out,
                                                 u16* __restrict__ vt,
                                                 int M, int N, int K) {
    __shared__ u16 As[3 * 128 * 32];   // 24 KB
    __shared__ u16 Bs[3 * 256 * 32];   // 48 KB
    const int tid = threadIdx.x, lane = tid & 63;
    const int l15 = lane & 15, lg = lane >> 4;
    const int nx = gridDim.x;
    const int bid = blockIdx.y * nx + blockIdx.x;
    const int xcd = bid & 7;
    const int c = bid >> 3;
    int mBase, nBase;
    if (MFAST) {
        const int mh = gridDim.y >> 3;
        mBase = (xcd * mh + (c % mh)) * 128;
        nBase = (c / mh) * 256;
    } else {
        const int q = (nx * gridDim.y) >> 3;
        const int swz = xcd * q + c;
        mBase = (swz / nx) * 128;
        nBase = (swz % nx) * 256;
    }
    const int w = tid >> 6, wr = w >> 1, wc = w & 1;

    // staging: A 512 chunks (2/thread), B 1024 chunks (4/thread); same row/swizzle calc
    const int srow = tid >> 2;                       // 0..63
    const int sg = ((tid & 3) ^ ((srow >> 1) & 3)) << 3;
    const u16* aCur = A + (size_t)(mBase + srow) * K + sg;   // rows srow, srow+64
    const u16* bCur = BT + (size_t)(nBase + srow) * K + sg;  // rows srow+{0,64,128,192}
    const size_t r64 = (size_t)64 * K;

    int offA[4], offB[8];
#pragma unroll
    for (int i = 0; i < 4; ++i) {
        int rA = wr * 64 + i * 16 + l15;
        offA[i] = rA * 32 + ((lg ^ ((rA >> 1) & 3)) << 3);
    }
#pragma unroll
    for (int i = 0; i < 8; ++i) {
        int rB = wc * 128 + i * 16 + l15;
        offB[i] = rB * 32 + ((lg ^ ((rB >> 1) & 3)) << 3);
    }

    f32x4 acc[4][8] = {};
    const int nsteps = K >> 5;   // 24 or 96: divisible by 3

    auto stage = [&](u16* sa, u16* sb, int ofs) {
        async16(sa + tid * 8, aCur + ofs);
        async16(sa + (256 + tid) * 8, aCur + r64 + ofs);
        async16(sb + tid * 8, bCur + ofs);
        async16(sb + (256 + tid) * 8, bCur + r64 + ofs);
        async16(sb + (512 + tid) * 8, bCur + 2 * r64 + ofs);
        async16(sb + (768 + tid) * 8, bCur + 3 * r64 + ofs);
    };

    stage(As, Bs, 0);                    // k=0 -> slot0
    stage(As + 4096, Bs + 8192, 32);     // k=1 -> slot1

    auto step = [&](int slot, int kk, int stageOfs) {
        if (kk + 1 < nsteps) {
            asm volatile("s_waitcnt vmcnt(6)" ::: "memory");
        } else {
            asm volatile("s_waitcnt vmcnt(0)" ::: "memory");
        }
        __builtin_amdgcn_s_barrier();
        asm volatile("" ::: "memory");
        if (kk + 2 < nsteps) {
            int ns = slot + 2;
            if (ns >= 3) ns -= 3;                  // literal-folded
            stage(As + ns * 4096, Bs + ns * 8192, stageOfs);
        }
        const u16* sA = As + slot * 4096;
        const u16* sB = Bs + slot * 8192;
        bf16x8 af[4], bfr[8];
#pragma unroll
        for (int mi = 0; mi < 4; ++mi) af[mi] = load8(sA + offA[mi]);
#pragma unroll
        for (int ni = 0; ni < 8; ++ni) bfr[ni] = load8(sB + offB[ni]);
        __builtin_amdgcn_s_setprio(1);
#pragma unroll
        for (int mi = 0; mi < 4; ++mi)
#pragma unroll
            for (int ni = 0; ni < 8; ++ni)
                acc[mi][ni] = __builtin_amdgcn_mfma_f32_16x16x32_bf16(
                    af[mi], bfr[ni], acc[mi][ni], 0, 0, 0);
        __builtin_amdgcn_s_setprio(0);
        asm volatile("" ::: "memory");
    };

    for (int kk = 0; kk < nsteps; kk += 3) {
        step(0, kk, 64);
        step(1, kk + 1, 96);
        step(2, kk + 2, 128);
        aCur += 96;
        bCur += 96;
    }

    const bool vtile = VOUT && (nBase >= 1536);
#pragma unroll
    for (int mi = 0; mi < 4; ++mi) {
#pragma unroll
        for (int ni = 0; ni < 8; ++ni) {
            const int row0 = mBase + wr * 64 + mi * 16 + lg * 4;
            const int col = nBase + wc * 128 + ni * 16 + l15;
            const float bv = bias[col];
            u16x4 cv;
#pragma unroll
            for (int r = 0; r < 4; ++r) {
                float v = acc[mi][ni][r] + bv;
                if (ACT == 1) v = gelu_t(v);
                u16 hv = f2b(v);
                cv[r] = hv;
                out[(size_t)(row0 + r) * N + col] = hv;
            }
            if (vtile) {
                const int dg = col - 1536;
                const int bh = (row0 >> 10) * 12 + (dg >> 6);
                const int d = dg & 63;
                const int t0 = row0 & 1023;
                *reinterpret_cast<u16x4*>(vt + (size_t)(bh * 64 + d) * 1024 + t0) = cv;
            }
        }
    }
}

// ------------- GEMM 128x128 (r17/r18 proven) for small-N shapes (proj, fc2) ----------
template <int ACT, int RESIDT, int OUTBF, int MFAST, int VOUT>
__global__ __launch_bounds__(256) void gemm_bt(const u16* __restrict__ A,
                                               const u16* __restrict__ BT,
                                               const float* __restrict__ bias,
                                               const void* __restrict__ resid,
                                               void* __restrict__ out,
                                               u16* __restrict__ vt,
                                               int M, int N, int K) {
    __shared__ u16 As[3 * 128 * 32];
    __shared__ u16 Bs[3 * 128 * 32];
    const int tid = threadIdx.x, lane = tid & 63;
    const int l15 = lane & 15, lg = lane >> 4;
    const int nx = gridDim.x;
    const int bid = blockIdx.y * nx + blockIdx.x;
    const int xcd = bid & 7;
    const int c = bid >> 3;
    int mBase, nBase;
    if (MFAST) {
        const int mh = gridDim.y >> 3;
        mBase = (xcd * mh + (c % mh)) * 128;
        nBase = (c / mh) * 128;
    } else {
        const int q = (nx * gridDim.y) >> 3;
        const int swz = xcd * q + c;
        mBase = (swz / nx) * 128;
        nBase = (swz % nx) * 128;
    }
    const int w = tid >> 6, wr = w >> 1, wc = w & 1;

    const int srow = tid >> 2;
    const int sg = ((tid & 3) ^ ((srow >> 1) & 3)) << 3;
    const u16* aCur = A + (size_t)(mBase + srow) * K + sg;
    const u16* bCur = BT + (size_t)(nBase + srow) * K + sg;
    const size_t half = (size_t)64 * K;
    const int dst0 = tid * 8, dst1 = (256 + tid) * 8;

    int offA[4], offB[4];
#pragma unroll
    for (int i = 0; i < 4; ++i) {
        int rA = wr * 64 + i * 16 + l15;
        offA[i] = rA * 32 + ((lg ^ ((rA >> 1) & 3)) << 3);
        int rB = wc * 64 + i * 16 + l15;
        offB[i] = rB * 32 + ((lg ^ ((rB >> 1) & 3)) << 3);
    }

    f32x4 acc[4][4] = {};
    const int nsteps = K >> 5;

    {   // prologue: k=0 -> slot0, k=1 -> slot1
        async16(As + dst0, aCur);
        async16(As + dst1, aCur + half);
        async16(Bs + dst0, bCur);
        async16(Bs + dst1, bCur + half);
        async16(As + 4096 + dst0, aCur + 32);
        async16(As + 4096 + dst1, aCur + half + 32);
        async16(Bs + 4096 + dst0, bCur + 32);
        async16(Bs + 4096 + dst1, bCur + half + 32);
    }

    auto step = [&](int slot, int kk, int stageOfs) {
        if (kk + 1 < nsteps) {
            asm volatile("s_waitcnt vmcnt(4)" ::: "memory");
        } else {
            asm volatile("s_waitcnt vmcnt(0)" ::: "memory");
        }
        __builtin_amdgcn_s_barrier();
        asm volatile("" ::: "memory");
        if (kk + 2 < nsteps) {
            int ns = slot + 2;
            if (ns >= 3) ns -= 3;
            u16* sa = As + ns * 4096;
            u16* sb = Bs + ns * 4096;
            async16(sa + dst0, aCur + stageOfs);
            async16(sa + dst1, aCur + half + stageOfs);
            async16(sb + dst0, bCur + stageOfs);
            async16(sb + dst1, bCur + half + stageOfs);
        }
        const u16* sA = As + slot * 4096;
        const u16* sB = Bs + slot * 4096;
        bf16x8 af[4], bfr[4];
#pragma unroll
        for (int mi = 0; mi < 4; ++mi) af[mi] = load8(sA + offA[mi]);
#pragma unroll
        for (int ni = 0; ni < 4; ++ni) bfr[ni] = load8(sB + offB[ni]);
        __builtin_amdgcn_s_setprio(1);
#pragma unroll
        for (int mi = 0; mi < 4; ++mi)
#pragma unroll
            for (int ni = 0; ni < 4; ++ni)
                acc[mi][ni] = __builtin_amdgcn_mfma_f32_16x16x32_bf16(
                    af[mi], bfr[ni], acc[mi][ni], 0, 0, 0);
        __builtin_amdgcn_s_setprio(0);
        asm volatile("" ::: "memory");
    };

    for (int kk = 0; kk < nsteps; kk += 3) {
        step(0, kk, 64);
        step(1, kk + 1, 96);
        step(2, kk + 2, 128);
        aCur += 96;
        bCur += 96;
    }

    const bool vtile = VOUT && (nBase >= 1536);
#pragma unroll
    for (int mi = 0; mi < 4; ++mi) {
#pragma unroll
        for (int ni = 0; ni < 4; ++ni) {
            const int row0 = mBase + wr * 64 + mi * 16 + lg * 4;
            const int col = nBase + wc * 64 + ni * 16 + l15;
            const float bv = bias[col];
            u16x4 cv;
#pragma unroll
            for (int r = 0; r < 4; ++r) {
                float v = acc[mi][ni][r] + bv;
                if (ACT == 1) v = gelu_t(v);
                size_t off = (size_t)(row0 + r) * N + col;
                if (RESIDT == 1) v += ((const float*)resid)[off];
                if (RESIDT == 2) v += b2f(((const u16*)resid)[off]);
                if (OUTBF) {
                    u16 hv = f2b(v);
                    cv[r] = hv;
                    ((u16*)out)[off] = hv;
                } else {
                    ((float*)out)[off] = v;
                }
            }
            if (vtile) {
                const int dg = col - 1536;
                const int bh = (row0 >> 10) * 12 + (dg >> 6);
                const int d = dg & 63;
                const int t0 = row0 & 1023;
                *reinterpret_cast<u16x4*>(vt + (size_t)(bh * 64 + d) * 1024 + t0) = cv;
            }
        }
    }
}

// ------------- causal flash attention: swapped QK^T + in-register softmax -------------
__global__ __launch_bounds__(256, 3) void attn_k(const u16* __restrict__ qkv,
                                                 const u16* __restrict__ vT,
                                                 u16* __restrict__ y) {
    __shared__ u16 Ks[2][64 * 64];
    __shared__ u16 Vs[2][64 * 64];
    __shared__ u16 Ps[4][2][16 * 64];
    const int tid = threadIdx.x, lane = tid & 63, w = tid >> 6;
    const int bid = blockIdx.x;
    const uint32_t permPk = 2u | (7u << 3) | (1u << 6) | (4u << 9) | (6u << 12) |
                            (0u << 15) | (5u << 18) | (3u << 21);
    const int qt = (permPk >> (((bid + (bid >> 8)) & 7) * 3)) & 7;
    const int bh = ((bid >> 8) << 5) + ((bid & 255) >> 3);
    const int b = bh / 12, hd = bh % 12;
    const int l15 = lane & 15, lg = lane >> 4;
    const int r0 = qt * 128 + w * 32;

    const float qscale = 0.125f * 1.4426950408889634f;
    bf16x8 qf[2][2];
#pragma unroll
    for (int m = 0; m < 2; ++m) {
        const u16* qb = qkv + (size_t)(b * 1024 + r0 + m * 16 + l15) * 2304 + hd * 64;
#pragma unroll
        for (int ks = 0; ks < 2; ++ks) {
            u16x8 u = *reinterpret_cast<const u16x8*>(qb + ks * 32 + lg * 8);
            u16x8 o;
#pragma unroll
            for (int jj = 0; jj < 8; ++jj) o[jj] = f2b(b2f(u[jj]) * qscale);
            qf[m][ks] = __builtin_bit_cast(bf16x8, o);
        }
    }

    const int srow = tid >> 3;
    const int ssc = ((tid & 7) ^ (srow & 7)) << 3;
    const u16* kSrc = qkv + (size_t)(b * 1024 + srow) * 2304 + 768 + hd * 64 + ssc;
    const u16* vSrc = vT + (size_t)(bh * 64 + srow) * 1024 + ssc;
    const int dst0 = tid * 8, dst1 = (256 + tid) * 8;

    auto stage = [&](int buf, int j) {
        const size_t kOff = (size_t)j * 64 * 2304;
        const int vOff = j * 64;
        async16(Ks[buf] + dst0, kSrc + kOff);
        async16(Ks[buf] + dst1, kSrc + kOff + (size_t)32 * 2304);
        async16(Vs[buf] + dst0, vSrc + vOff);
        async16(Vs[buf] + dst1, vSrc + vOff + 32 * 1024);
    };

    f32x4 oacc[2][4] = {};
    float mrow[2] = {-1e30f, -1e30f};
    float lrow[2] = {0.f, 0.f};

    const int jd = (r0 + 31) >> 6;
    const int jmax = qt * 2 + 1;

    stage(0, 0);
    for (int j = 0; j <= jmax; ++j) {
        const int cur = j & 1;
        if (j < jmax) {
            stage(cur ^ 1, j + 1);
            asm volatile("s_waitcnt vmcnt(4)" ::: "memory");
        } else {
            asm volatile("s_waitcnt vmcnt(0)" ::: "memory");
        }
        __builtin_amdgcn_s_barrier();
        asm volatile("" ::: "memory");

        if (j <= jd) {
            const bool diag = (j == jd);
            const u16* Kc = Ks[cur];
            const u16* Vc = Vs[cur];
            f32x4 s[2][4] = {};
            __builtin_amdgcn_s_setprio(1);
#pragma unroll
            for (int ks = 0; ks < 2; ++ks) {
                bf16x8 kf[4];
#pragma unroll
                for (int ni = 0; ni < 4; ++ni) {
                    int key = ni * 16 + l15;
                    kf[ni] = load8(Kc + key * 64 + (((ks * 4 + lg) ^ (key & 7)) << 3));
                }
#pragma unroll
                for (int ni = 0; ni < 4; ++ni) {
                    s[0][ni] = __builtin_amdgcn_mfma_f32_16x16x32_bf16(
                        kf[ni], qf[0][ks], s[0][ni], 0, 0, 0);
                    s[1][ni] = __builtin_amdgcn_mfma_f32_16x16x32_bf16(
                        kf[ni], qf[1][ks], s[1][ni], 0, 0, 0);
                }
            }
            __builtin_amdgcn_s_setprio(0);

#pragma unroll
            for (int m = 0; m < 2; ++m) {
                if (diag) {
                    const int qrow = r0 + m * 16 + l15;
#pragma unroll
                    for (int ni = 0; ni < 4; ++ni) {
                        int key = j * 64 + ni * 16 + lg * 4;
#pragma unroll
                        for (int r = 0; r < 4; ++r)
                            if (key + r > qrow) s[m][ni][r] = -1e30f;
                    }
                }
                float pmax = -1e30f;
#pragma unroll
                for (int ni = 0; ni < 4; ++ni)
#pragma unroll
                    for (int r = 0; r < 4; ++r) pmax = fmaxf(pmax, s[m][ni][r]);
                pmax = fmaxf(pmax, __shfl_xor(pmax, 16));
                pmax = fmaxf(pmax, __shfl_xor(pmax, 32));

                if (!__all(pmax <= mrow[m] + 8.0f)) {
                    float mnew = fmaxf(mrow[m], pmax);
                    float scal = exp2f(mrow[m] - mnew);
                    mrow[m] = mnew;
                    lrow[m] *= scal;
#pragma unroll
                    for (int r = 0; r < 4; ++r) {
                        float sr = __shfl(scal, lg * 4 + r);
#pragma unroll
                        for (int ni = 0; ni < 4; ++ni) oacc[m][ni][r] *= sr;
                    }
                }
                float psum = 0.f;
#pragma unroll
                for (int ni = 0; ni < 4; ++ni) {
                    u16x4 pk;
#pragma unroll
                    for (int r = 0; r < 4; ++r) {
                        float pv = exp2f(s[m][ni][r] - mrow[m]);
                        psum += pv;
                        pk[r] = f2b(pv);
                    }
                    *reinterpret_cast<u16x4*>(
                        &Ps[w][m][l15 * 64 + ((ni * 16 + lg * 4) ^ ((l15 & 7) << 3))]) =
                        pk;
                }
                psum += __shfl_xor(psum, 16);
                psum += __shfl_xor(psum, 32);
                lrow[m] += psum;
            }

            __builtin_amdgcn_s_setprio(1);
#pragma unroll
            for (int ks = 0; ks < 2; ++ks) {
                bf16x8 pf0 = load8(
                    &Ps[w][0][l15 * 64 + ((ks * 32 + lg * 8) ^ ((l15 & 7) << 3))]);
                bf16x8 pf1 = load8(
                    &Ps[w][1][l15 * 64 + ((ks * 32 + lg * 8) ^ ((l15 & 7) << 3))]);
                bf16x8 vf[4];
#pragma unroll
                for (int ni = 0; ni < 4; ++ni) {
                    int d = ni * 16 + l15;
                    vf[ni] = load8(Vc + d * 64 + (((ks * 4 + lg) ^ (d & 7)) << 3));
                }
#pragma unroll
                for (int ni = 0; ni < 4; ++ni) {
                    oacc[0][ni] = __builtin_amdgcn_mfma_f32_16x16x32_bf16(
                        pf0, vf[ni], oacc[0][ni], 0, 0, 0);
                    oacc[1][ni] = __builtin_amdgcn_mfma_f32_16x16x32_bf16(
                        pf1, vf[ni], oacc[1][ni], 0, 0, 0);
                }
            }
            __builtin_amdgcn_s_setprio(0);
        }
        asm volatile("" ::: "memory");
        __builtin_amdgcn_s_barrier();
        asm volatile("" ::: "memory");
    }

#pragma unroll
    for (int m = 0; m < 2; ++m) {
#pragma unroll
        for (int r = 0; r < 4; ++r) {
            float rl = 1.0f / __shfl(lrow[m], lg * 4 + r);
            int row = r0 + m * 16 + lg * 4 + r;
#pragma unroll
            for (int ni = 0; ni < 4; ++ni) {
                int col = hd * 64 + ni * 16 + l15;
                y[(size_t)(b * 1024 + row) * 768 + col] = f2b(oacc[m][ni][r] * rl);
            }
        }
    }
}

extern "C" void kernel_launch(void* const* d_in, const int* in_sizes, int n_in,
                              void* d_out, int out_size, void* d_ws, size_t ws_size,
                              hipStream_t stream) {
    const float* x      = (const float*)d_in[0];
    const float* ln1_g  = (const float*)d_in[1];
    const float* ln1_b  = (const float*)d_in[2];
    const float* w_attn = (const float*)d_in[3];
    const float* b_attn = (const float*)d_in[4];
    const float* w_proj = (const float*)d_in[5];
    const float* b_proj = (const float*)d_in[6];
    const float* ln2_g  = (const float*)d_in[7];
    const float* ln2_b  = (const float*)d_in[8];
    const float* w_fc1  = (const float*)d_in[9];
    const float* b_fc1  = (const float*)d_in[10];
    const float* w_fc2  = (const float*)d_in[11];
    const float* b_fc2  = (const float*)d_in[12];
    float* out = (float*)d_out;

    char* p = (char*)d_ws;
    auto take = [&](size_t n) {
        char* r = p;
        p += (n + 255) & ~(size_t)255;
        return r;
    };
    u16* wT_attn = (u16*)take((size_t)2304 * 768 * 2);
    u16* wT_proj = (u16*)take((size_t)768 * 768 * 2);
    u16* wT_fc1  = (u16*)take((size_t)3072 * 768 * 2);
    u16* wT_fc2  = (u16*)take((size_t)768 * 3072 * 2);
    u16* h       = (u16*)take((size_t)8192 * 768 * 2);   // h1 / h2 (aliased)
    u16* bufA    = (u16*)take((size_t)50331648);         // qkv+vT, later g1
    u16* yb      = (u16*)take((size_t)8192 * 768 * 2);
    u16* x1b     = (u16*)take((size_t)8192 * 768 * 2);   // residual stream, bf16
    u16* qkv = bufA;
    u16* vT  = bufA + (size_t)8192 * 2304;
    u16* g1  = bufA;

    const dim3 tb(32, 8);
    // fused: weight transposes + ln1
    prep_k<<<8960, tb, 0, stream>>>(w_attn, w_proj, w_fc1, w_fc2,
                                    wT_attn, wT_proj, wT_fc1, wT_fc2,
                                    x, ln1_g, ln1_b, h);
    // qkv = h @ w_attn + b_attn -> bf16 (wide tile, fused V-transpose)
    gemm_wide<0, 1, 1><<<dim3(9, 64), 256, 0, stream>>>(h, wT_attn, b_attn, qkv, vT,
                                                        8192, 2304, 768);
    // attention
    attn_k<<<768, 256, 0, stream>>>(qkv, vT, yb);
    // x1b = bf16(x + y @ w_proj + b_proj)
    gemm_bt<0, 1, 1, 1, 0><<<dim3(6, 64), 256, 0, stream>>>(
        yb, wT_proj, b_proj, x, x1b, nullptr, 8192, 768, 768);
    // ln2 (bf16 input)
    ln_b16<<<2048, 256, 0, stream>>>(x1b, ln2_g, ln2_b, h);
    // g1 = gelu(h @ w_fc1 + b_fc1) -> bf16 (wide tile)
    gemm_wide<1, 1, 0><<<dim3(12, 64), 256, 0, stream>>>(h, wT_fc1, b_fc1, g1, nullptr,
                                                         8192, 3072, 768);
    // out = x1b + g1 @ w_fc2 + b_fc2  (fp32 out, bf16 resid; n-fastest)
    gemm_bt<0, 2, 0, 0, 0><<<dim3(6, 64), 256, 0, stream>>>(
        g1, wT_fc2, b_fc2, x1b, out, nullptr, 8192, 768, 3072);
}

// Round 20
// 242.671 us; speedup vs baseline: 1.0997x; 1.0997x over previous
//
#include <hip/hip_runtime.h>
#include <cstdint>
#include <cmath>

typedef unsigned short u16;
typedef __bf16 bf16_t;
typedef bf16_t bf16x8 __attribute__((ext_vector_type(8)));
typedef float f32x4 __attribute__((ext_vector_type(4)));
typedef u16 u16x8 __attribute__((ext_vector_type(8)));
typedef u16 u16x4 __attribute__((ext_vector_type(4)));

#define DEV __device__ __forceinline__

DEV u16 f2b(float f) {
    uint32_t u = __builtin_bit_cast(uint32_t, f);
    u += 0x7FFFu + ((u >> 16) & 1u);
    return (u16)(u >> 16);
}
DEV float b2f(u16 h) { return __builtin_bit_cast(float, (uint32_t)h << 16); }

DEV bf16x8 load8(const u16* p) {
    return __builtin_bit_cast(bf16x8, *reinterpret_cast<const u16x8*>(p));
}

DEV void async16(void* lds, const void* g) {
    __builtin_amdgcn_global_load_lds(
        reinterpret_cast<const __attribute__((address_space(1))) void*>(
            reinterpret_cast<uintptr_t>(g)),
        reinterpret_cast<__attribute__((address_space(3))) void*>(
            reinterpret_cast<uintptr_t>(lds)),
        16, 0, 0);
}

DEV float gelu_t(float x) {
    float z = 0.7978845608028654f * (x + 0.044715f * x * x * x);
    z = fminf(fmaxf(z, -15.0f), 15.0f);
    float e = __expf(2.0f * z);
    return 0.5f * x * (1.0f + (e - 1.0f) / (e + 1.0f));
}

// ------- prep: all 4 weight transposes (blocks 0..6911) + ln1 (blocks 6912..8959) -----
__global__ __launch_bounds__(256) void prep_k(const float* __restrict__ w0,
                                              const float* __restrict__ w1,
                                              const float* __restrict__ w2,
                                              const float* __restrict__ w3,
                                              u16* __restrict__ o0, u16* __restrict__ o1,
                                              u16* __restrict__ o2, u16* __restrict__ o3,
                                              const float* __restrict__ x,
                                              const float* __restrict__ g,
                                              const float* __restrict__ bb,
                                              u16* __restrict__ h) {
    __shared__ float tile[32][33];
    const int id = blockIdx.x;
    const int tx = threadIdx.x, ty = threadIdx.y;
    if (id < 6912) {
        const float* W;
        u16* WT;
        int K, N, loc;
        if (id < 1728) {            // w_attn 768x2304: 72x24 tiles
            W = w0; WT = o0; K = 768; N = 2304; loc = id;
        } else if (id < 2304) {     // w_proj 768x768
            W = w1; WT = o1; K = 768; N = 768; loc = id - 1728;
        } else if (id < 4608) {     // w_fc1 768x3072
            W = w2; WT = o2; K = 768; N = 3072; loc = id - 2304;
        } else {                    // w_fc2 3072x768
            W = w3; WT = o3; K = 3072; N = 768; loc = id - 4608;
        }
        const int nx = N >> 5;
        const int n0 = (loc % nx) * 32, k0 = (loc / nx) * 32;
#pragma unroll
        for (int i = 0; i < 4; ++i)
            tile[ty + i * 8][tx] = W[(size_t)(k0 + ty + i * 8) * N + n0 + tx];
        __syncthreads();
#pragma unroll
        for (int i = 0; i < 4; ++i)
            WT[(size_t)(n0 + ty + i * 8) * K + k0 + tx] = f2b(tile[tx][ty + i * 8]);
    } else {
        const int flat = ty * 32 + tx;
        const int lane = flat & 63, w = flat >> 6;
        const int row = (id - 6912) * 4 + w;
        const float4* xr = reinterpret_cast<const float4*>(x + (size_t)row * 768);
        float4 v[3];
        float s = 0.f, s2 = 0.f;
#pragma unroll
        for (int i = 0; i < 3; ++i) {
            v[i] = xr[i * 64 + lane];
            s += v[i].x + v[i].y + v[i].z + v[i].w;
            s2 += v[i].x * v[i].x + v[i].y * v[i].y + v[i].z * v[i].z + v[i].w * v[i].w;
        }
#pragma unroll
        for (int off = 1; off < 64; off <<= 1) {
            s += __shfl_xor(s, off);
            s2 += __shfl_xor(s2, off);
        }
        const float mu = s * (1.0f / 768.0f);
        const float rstd = rsqrtf(s2 * (1.0f / 768.0f) - mu * mu + 1e-5f);
#pragma unroll
        for (int i = 0; i < 3; ++i) {
            int col = i * 256 + lane * 4;
            u16x4 o;
            o[0] = f2b((v[i].x - mu) * rstd * g[col + 0] + bb[col + 0]);
            o[1] = f2b((v[i].y - mu) * rstd * g[col + 1] + bb[col + 1]);
            o[2] = f2b((v[i].z - mu) * rstd * g[col + 2] + bb[col + 2]);
            o[3] = f2b((v[i].w - mu) * rstd * g[col + 3] + bb[col + 3]);
            *reinterpret_cast<u16x4*>(h + (size_t)row * 768 + col) = o;
        }
    }
}

// ---------------- LayerNorm bf16-in: 1 wave per row of 768 -> bf16 ----------------
__global__ __launch_bounds__(256) void ln_b16(const u16* __restrict__ x,
                                              const float* __restrict__ g,
                                              const float* __restrict__ bb,
                                              u16* __restrict__ out) {
    const int lane = threadIdx.x & 63, w = threadIdx.x >> 6;
    const int row = blockIdx.x * 4 + w;
    const u16* xr = x + (size_t)row * 768;
    float v[12];
    float s = 0.f, s2 = 0.f;
#pragma unroll
    for (int i = 0; i < 3; ++i) {
        u16x4 u = *reinterpret_cast<const u16x4*>(xr + i * 256 + lane * 4);
#pragma unroll
        for (int jj = 0; jj < 4; ++jj) {
            float f = b2f(u[jj]);
            v[i * 4 + jj] = f;
            s += f;
            s2 += f * f;
        }
    }
#pragma unroll
    for (int off = 1; off < 64; off <<= 1) {
        s += __shfl_xor(s, off);
        s2 += __shfl_xor(s2, off);
    }
    const float mu = s * (1.0f / 768.0f);
    const float rstd = rsqrtf(s2 * (1.0f / 768.0f) - mu * mu + 1e-5f);
#pragma unroll
    for (int i = 0; i < 3; ++i) {
        int col = i * 256 + lane * 4;
        u16x4 o;
#pragma unroll
        for (int jj = 0; jj < 4; ++jj)
            o[jj] = f2b((v[i * 4 + jj] - mu) * rstd * g[col + jj] + bb[col + jj]);
        *reinterpret_cast<u16x4*>(out + (size_t)row * 768 + col) = o;
    }
}

// ------------- GEMM 128x128, BK=32, 4 waves, 3-slot rotation, 1 barrier/K-step ------
// K-loop unrolled in groups of 3; slot indices literal. MFAST=1: m-fastest XCD decode.
// RESIDT: 0 none, 1 fp32, 2 bf16. VOUT=1: V-region tiles (nBase>=1536) also scatter
// transposed u16x4 stores into vT (fuses the old vtrans kernel).
template <int ACT, int RESIDT, int OUTBF, int MFAST, int VOUT>
__global__ __launch_bounds__(256) void gemm_bt(const u16* __restrict__ A,
                                               const u16* __restrict__ BT,
                                               const float* __restrict__ bias,
                                               const void* __restrict__ resid,
                                               void* __restrict__ out,
                                               u16* __restrict__ vt,
                                               int M, int N, int K) {
    __shared__ u16 As[3 * 128 * 32];
    __shared__ u16 Bs[3 * 128 * 32];
    const int tid = threadIdx.x, lane = tid & 63;
    const int l15 = lane & 15, lg = lane >> 4;
    const int nx = gridDim.x;
    const int bid = blockIdx.y * nx + blockIdx.x;
    const int xcd = bid & 7;
    const int c = bid >> 3;
    int mBase, nBase;
    if (MFAST) {
        const int mh = gridDim.y >> 3;
        mBase = (xcd * mh + (c % mh)) * 128;
        nBase = (c / mh) * 128;
    } else {
        const int q = (nx * gridDim.y) >> 3;
        const int swz = xcd * q + c;
        mBase = (swz / nx) * 128;
        nBase = (swz % nx) * 128;
    }
    const int w = tid >> 6, wr = w >> 1, wc = w & 1;

    const int srow = tid >> 2;
    const int sg = ((tid & 3) ^ ((srow >> 1) & 3)) << 3;
    const u16* aCur = A + (size_t)(mBase + srow) * K + sg;
    const u16* bCur = BT + (size_t)(nBase + srow) * K + sg;
    const size_t half = (size_t)64 * K;
    const int dst0 = tid * 8, dst1 = (256 + tid) * 8;

    int offA[4], offB[4];
#pragma unroll
    for (int i = 0; i < 4; ++i) {
        int rA = wr * 64 + i * 16 + l15;
        offA[i] = rA * 32 + ((lg ^ ((rA >> 1) & 3)) << 3);
        int rB = wc * 64 + i * 16 + l15;
        offB[i] = rB * 32 + ((lg ^ ((rB >> 1) & 3)) << 3);
    }

    f32x4 acc[4][4] = {};
    const int nsteps = K >> 5;   // 24 or 96: divisible by 3

    {   // prologue: k=0 -> slot0, k=1 -> slot1
        async16(As + dst0, aCur);
        async16(As + dst1, aCur + half);
        async16(Bs + dst0, bCur);
        async16(Bs + dst1, bCur + half);
        async16(As + 4096 + dst0, aCur + 32);
        async16(As + 4096 + dst1, aCur + half + 32);
        async16(Bs + 4096 + dst0, bCur + 32);
        async16(Bs + 4096 + dst1, bCur + half + 32);
    }

    auto step = [&](int slot, int kk, int stageOfs) {
        if (kk + 1 < nsteps) {
            asm volatile("s_waitcnt vmcnt(4)" ::: "memory");
        } else {
            asm volatile("s_waitcnt vmcnt(0)" ::: "memory");
        }
        __builtin_amdgcn_s_barrier();
        asm volatile("" ::: "memory");
        if (kk + 2 < nsteps) {
            int ns = slot + 2;
            if (ns >= 3) ns -= 3;
            u16* sa = As + ns * 4096;
            u16* sb = Bs + ns * 4096;
            async16(sa + dst0, aCur + stageOfs);
            async16(sa + dst1, aCur + half + stageOfs);
            async16(sb + dst0, bCur + stageOfs);
            async16(sb + dst1, bCur + half + stageOfs);
        }
        const u16* sA = As + slot * 4096;
        const u16* sB = Bs + slot * 4096;
        bf16x8 af[4], bfr[4];
#pragma unroll
        for (int mi = 0; mi < 4; ++mi) af[mi] = load8(sA + offA[mi]);
#pragma unroll
        for (int ni = 0; ni < 4; ++ni) bfr[ni] = load8(sB + offB[ni]);
        __builtin_amdgcn_s_setprio(1);
#pragma unroll
        for (int mi = 0; mi < 4; ++mi)
#pragma unroll
            for (int ni = 0; ni < 4; ++ni)
                acc[mi][ni] = __builtin_amdgcn_mfma_f32_16x16x32_bf16(
                    af[mi], bfr[ni], acc[mi][ni], 0, 0, 0);
        __builtin_amdgcn_s_setprio(0);
        asm volatile("" ::: "memory");
    };

    for (int kk = 0; kk < nsteps; kk += 3) {
        step(0, kk, 64);
        step(1, kk + 1, 96);
        step(2, kk + 2, 128);
        aCur += 96;
        bCur += 96;
    }

    const bool vtile = VOUT && (nBase >= 1536);
#pragma unroll
    for (int mi = 0; mi < 4; ++mi) {
#pragma unroll
        for (int ni = 0; ni < 4; ++ni) {
            const int row0 = mBase + wr * 64 + mi * 16 + lg * 4;
            const int col = nBase + wc * 64 + ni * 16 + l15;
            const float bv = bias[col];
            u16x4 cv;
#pragma unroll
            for (int r = 0; r < 4; ++r) {
                float v = acc[mi][ni][r] + bv;
                if (ACT == 1) v = gelu_t(v);
                size_t off = (size_t)(row0 + r) * N + col;
                if (RESIDT == 1) v += ((const float*)resid)[off];
                if (RESIDT == 2) v += b2f(((const u16*)resid)[off]);
                if (OUTBF) {
                    u16 hv = f2b(v);
                    cv[r] = hv;
                    ((u16*)out)[off] = hv;
                } else {
                    ((float*)out)[off] = v;
                }
            }
            if (vtile) {
                // transposed V copy: 4 consecutive t-values at fixed d
                const int dg = col - 1536;                    // 0..767
                const int bh = (row0 >> 10) * 12 + (dg >> 6); // batch*12 + head
                const int d = dg & 63;
                const int t0 = row0 & 1023;
                *reinterpret_cast<u16x4*>(vt + (size_t)(bh * 64 + d) * 1024 + t0) = cv;
            }
        }
    }
}

// ------------- causal flash attention: swapped QK^T + in-register softmax -------------
__global__ __launch_bounds__(256, 3) void attn_k(const u16* __restrict__ qkv,
                                                 const u16* __restrict__ vT,
                                                 u16* __restrict__ y) {
    __shared__ u16 Ks[2][64 * 64];
    __shared__ u16 Vs[2][64 * 64];
    __shared__ u16 Ps[4][2][16 * 64];
    const int tid = threadIdx.x, lane = tid & 63, w = tid >> 6;
    const int bid = blockIdx.x;
    const uint32_t permPk = 2u | (7u << 3) | (1u << 6) | (4u << 9) | (6u << 12) |
                            (0u << 15) | (5u << 18) | (3u << 21);
    const int qt = (permPk >> (((bid + (bid >> 8)) & 7) * 3)) & 7;
    const int bh = ((bid >> 8) << 5) + ((bid & 255) >> 3);
    const int b = bh / 12, hd = bh % 12;
    const int l15 = lane & 15, lg = lane >> 4;
    const int r0 = qt * 128 + w * 32;

    const float qscale = 0.125f * 1.4426950408889634f;
    bf16x8 qf[2][2];
#pragma unroll
    for (int m = 0; m < 2; ++m) {
        const u16* qb = qkv + (size_t)(b * 1024 + r0 + m * 16 + l15) * 2304 + hd * 64;
#pragma unroll
        for (int ks = 0; ks < 2; ++ks) {
            u16x8 u = *reinterpret_cast<const u16x8*>(qb + ks * 32 + lg * 8);
            u16x8 o;
#pragma unroll
            for (int jj = 0; jj < 8; ++jj) o[jj] = f2b(b2f(u[jj]) * qscale);
            qf[m][ks] = __builtin_bit_cast(bf16x8, o);
        }
    }

    const int srow = tid >> 3;
    const int ssc = ((tid & 7) ^ (srow & 7)) << 3;
    const u16* kSrc = qkv + (size_t)(b * 1024 + srow) * 2304 + 768 + hd * 64 + ssc;
    const u16* vSrc = vT + (size_t)(bh * 64 + srow) * 1024 + ssc;
    const int dst0 = tid * 8, dst1 = (256 + tid) * 8;

    auto stage = [&](int buf, int j) {
        const size_t kOff = (size_t)j * 64 * 2304;
        const int vOff = j * 64;
        async16(Ks[buf] + dst0, kSrc + kOff);
        async16(Ks[buf] + dst1, kSrc + kOff + (size_t)32 * 2304);
        async16(Vs[buf] + dst0, vSrc + vOff);
        async16(Vs[buf] + dst1, vSrc + vOff + 32 * 1024);
    };

    f32x4 oacc[2][4] = {};
    float mrow[2] = {-1e30f, -1e30f};
    float lrow[2] = {0.f, 0.f};

    const int jd = (r0 + 31) >> 6;
    const int jmax = qt * 2 + 1;

    stage(0, 0);
    for (int j = 0; j <= jmax; ++j) {
        const int cur = j & 1;
        if (j < jmax) {
            stage(cur ^ 1, j + 1);
            asm volatile("s_waitcnt vmcnt(4)" ::: "memory");
        } else {
            asm volatile("s_waitcnt vmcnt(0)" ::: "memory");
        }
        __builtin_amdgcn_s_barrier();
        asm volatile("" ::: "memory");

        if (j <= jd) {
            const bool diag = (j == jd);
            const u16* Kc = Ks[cur];
            const u16* Vc = Vs[cur];
            f32x4 s[2][4] = {};
            __builtin_amdgcn_s_setprio(1);
#pragma unroll
            for (int ks = 0; ks < 2; ++ks) {
                bf16x8 kf[4];
#pragma unroll
                for (int ni = 0; ni < 4; ++ni) {
                    int key = ni * 16 + l15;
                    kf[ni] = load8(Kc + key * 64 + (((ks * 4 + lg) ^ (key & 7)) << 3));
                }
#pragma unroll
                for (int ni = 0; ni < 4; ++ni) {
                    s[0][ni] = __builtin_amdgcn_mfma_f32_16x16x32_bf16(
                        kf[ni], qf[0][ks], s[0][ni], 0, 0, 0);
                    s[1][ni] = __builtin_amdgcn_mfma_f32_16x16x32_bf16(
                        kf[ni], qf[1][ks], s[1][ni], 0, 0, 0);
                }
            }
            __builtin_amdgcn_s_setprio(0);

#pragma unroll
            for (int m = 0; m < 2; ++m) {
                if (diag) {
                    const int qrow = r0 + m * 16 + l15;
#pragma unroll
                    for (int ni = 0; ni < 4; ++ni) {
                        int key = j * 64 + ni * 16 + lg * 4;
#pragma unroll
                        for (int r = 0; r < 4; ++r)
                            if (key + r > qrow) s[m][ni][r] = -1e30f;
                    }
                }
                float pmax = -1e30f;
#pragma unroll
                for (int ni = 0; ni < 4; ++ni)
#pragma unroll
                    for (int r = 0; r < 4; ++r) pmax = fmaxf(pmax, s[m][ni][r]);
                pmax = fmaxf(pmax, __shfl_xor(pmax, 16));
                pmax = fmaxf(pmax, __shfl_xor(pmax, 32));

                if (!__all(pmax <= mrow[m] + 8.0f)) {
                    float mnew = fmaxf(mrow[m], pmax);
                    float scal = exp2f(mrow[m] - mnew);
                    mrow[m] = mnew;
                    lrow[m] *= scal;
#pragma unroll
                    for (int r = 0; r < 4; ++r) {
                        float sr = __shfl(scal, lg * 4 + r);
#pragma unroll
                        for (int ni = 0; ni < 4; ++ni) oacc[m][ni][r] *= sr;
                    }
                }
                float psum = 0.f;
#pragma unroll
                for (int ni = 0; ni < 4; ++ni) {
                    u16x4 pk;
#pragma unroll
                    for (int r = 0; r < 4; ++r) {
                        float pv = exp2f(s[m][ni][r] - mrow[m]);
                        psum += pv;
                        pk[r] = f2b(pv);
                    }
                    *reinterpret_cast<u16x4*>(
                        &Ps[w][m][l15 * 64 + ((ni * 16 + lg * 4) ^ ((l15 & 7) << 3))]) =
                        pk;
                }
                psum += __shfl_xor(psum, 16);
                psum += __shfl_xor(psum, 32);
                lrow[m] += psum;
            }

            __builtin_amdgcn_s_setprio(1);
#pragma unroll
            for (int ks = 0; ks < 2; ++ks) {
                bf16x8 pf0 = load8(
                    &Ps[w][0][l15 * 64 + ((ks * 32 + lg * 8) ^ ((l15 & 7) << 3))]);
                bf16x8 pf1 = load8(
                    &Ps[w][1][l15 * 64 + ((ks * 32 + lg * 8) ^ ((l15 & 7) << 3))]);
                bf16x8 vf[4];
#pragma unroll
                for (int ni = 0; ni < 4; ++ni) {
                    int d = ni * 16 + l15;
                    vf[ni] = load8(Vc + d * 64 + (((ks * 4 + lg) ^ (d & 7)) << 3));
                }
#pragma unroll
                for (int ni = 0; ni < 4; ++ni) {
                    oacc[0][ni] = __builtin_amdgcn_mfma_f32_16x16x32_bf16(
                        pf0, vf[ni], oacc[0][ni], 0, 0, 0);
                    oacc[1][ni] = __builtin_amdgcn_mfma_f32_16x16x32_bf16(
                        pf1, vf[ni], oacc[1][ni], 0, 0, 0);
                }
            }
            __builtin_amdgcn_s_setprio(0);
        }
        asm volatile("" ::: "memory");
        __builtin_amdgcn_s_barrier();
        asm volatile("" ::: "memory");
    }

#pragma unroll
    for (int m = 0; m < 2; ++m) {
#pragma unroll
        for (int r = 0; r < 4; ++r) {
            float rl = 1.0f / __shfl(lrow[m], lg * 4 + r);
            int row = r0 + m * 16 + lg * 4 + r;
#pragma unroll
            for (int ni = 0; ni < 4; ++ni) {
                int col = hd * 64 + ni * 16 + l15;
                y[(size_t)(b * 1024 + row) * 768 + col] = f2b(oacc[m][ni][r] * rl);
            }
        }
    }
}

extern "C" void kernel_launch(void* const* d_in, const int* in_sizes, int n_in,
                              void* d_out, int out_size, void* d_ws, size_t ws_size,
                              hipStream_t stream) {
    const float* x      = (const float*)d_in[0];
    const float* ln1_g  = (const float*)d_in[1];
    const float* ln1_b  = (const float*)d_in[2];
    const float* w_attn = (const float*)d_in[3];
    const float* b_attn = (const float*)d_in[4];
    const float* w_proj = (const float*)d_in[5];
    const float* b_proj = (const float*)d_in[6];
    const float* ln2_g  = (const float*)d_in[7];
    const float* ln2_b  = (const float*)d_in[8];
    const float* w_fc1  = (const float*)d_in[9];
    const float* b_fc1  = (const float*)d_in[10];
    const float* w_fc2  = (const float*)d_in[11];
    const float* b_fc2  = (const float*)d_in[12];
    float* out = (float*)d_out;

    char* p = (char*)d_ws;
    auto take = [&](size_t n) {
        char* r = p;
        p += (n + 255) & ~(size_t)255;
        return r;
    };
    u16* wT_attn = (u16*)take((size_t)2304 * 768 * 2);
    u16* wT_proj = (u16*)take((size_t)768 * 768 * 2);
    u16* wT_fc1  = (u16*)take((size_t)3072 * 768 * 2);
    u16* wT_fc2  = (u16*)take((size_t)768 * 3072 * 2);
    u16* h       = (u16*)take((size_t)8192 * 768 * 2);   // h1 / h2 (aliased)
    u16* bufA    = (u16*)take((size_t)50331648);         // qkv+vT, later g1
    u16* yb      = (u16*)take((size_t)8192 * 768 * 2);
    u16* x1b     = (u16*)take((size_t)8192 * 768 * 2);   // residual stream, bf16
    u16* qkv = bufA;
    u16* vT  = bufA + (size_t)8192 * 2304;
    u16* g1  = bufA;

    const dim3 tb(32, 8);
    // fused: weight transposes + ln1
    prep_k<<<8960, tb, 0, stream>>>(w_attn, w_proj, w_fc1, w_fc2,
                                    wT_attn, wT_proj, wT_fc1, wT_fc2,
                                    x, ln1_g, ln1_b, h);
    // qkv = h @ w_attn + b_attn -> bf16, with fused V-transpose into vT
    gemm_bt<0, 0, 1, 1, 1><<<dim3(18, 64), 256, 0, stream>>>(
        h, wT_attn, b_attn, nullptr, qkv, vT, 8192, 2304, 768);
    // attention
    attn_k<<<768, 256, 0, stream>>>(qkv, vT, yb);
    // x1b = bf16(x + y @ w_proj + b_proj)
    gemm_bt<0, 1, 1, 1, 0><<<dim3(6, 64), 256, 0, stream>>>(
        yb, wT_proj, b_proj, x, x1b, nullptr, 8192, 768, 768);
    // ln2 (bf16 input)
    ln_b16<<<2048, 256, 0, stream>>>(x1b, ln2_g, ln2_b, h);
    // g1 = gelu(h @ w_fc1 + b_fc1) -> bf16
    gemm_bt<1, 0, 1, 1, 0><<<dim3(24, 64), 256, 0, stream>>>(
        h, wT_fc1, b_fc1, nullptr, g1, nullptr, 8192, 3072, 768);
    // out = x1b + g1 @ w_fc2 + b_fc2  (fp32 out, bf16 resid; n-fastest)
    gemm_bt<0, 2, 0, 0, 0><<<dim3(6, 64), 256, 0, stream>>>(
        g1, wT_fc2, b_fc2, x1b, out, nullptr, 8192, 768, 3072);
}

// Round 21
// 242.398 us; speedup vs baseline: 1.1010x; 1.0011x over previous
//
#include <hip/hip_runtime.h>
#include <cstdint>
#include <cmath>

typedef unsigned short u16;
typedef __bf16 bf16_t;
typedef bf16_t bf16x8 __attribute__((ext_vector_type(8)));
typedef float f32x4 __attribute__((ext_vector_type(4)));
typedef u16 u16x8 __attribute__((ext_vector_type(8)));
typedef u16 u16x4 __attribute__((ext_vector_type(4)));

#define DEV __device__ __forceinline__

DEV u16 f2b(float f) {
    uint32_t u = __builtin_bit_cast(uint32_t, f);
    u += 0x7FFFu + ((u >> 16) & 1u);
    return (u16)(u >> 16);
}
DEV float b2f(u16 h) { return __builtin_bit_cast(float, (uint32_t)h << 16); }

DEV bf16x8 load8(const u16* p) {
    return __builtin_bit_cast(bf16x8, *reinterpret_cast<const u16x8*>(p));
}

DEV void async16(void* lds, const void* g) {
    __builtin_amdgcn_global_load_lds(
        reinterpret_cast<const __attribute__((address_space(1))) void*>(
            reinterpret_cast<uintptr_t>(g)),
        reinterpret_cast<__attribute__((address_space(3))) void*>(
            reinterpret_cast<uintptr_t>(lds)),
        16, 0, 0);
}

DEV float gelu_t(float x) {
    float z = 0.7978845608028654f * (x + 0.044715f * x * x * x);
    z = fminf(fmaxf(z, -15.0f), 15.0f);
    float e = __expf(2.0f * z);
    return 0.5f * x * (1.0f + (e - 1.0f) / (e + 1.0f));
}

// ------- prep: all 4 weight transposes (blocks 0..6911) + ln1 (blocks 6912..8959) -----
__global__ __launch_bounds__(256) void prep_k(const float* __restrict__ w0,
                                              const float* __restrict__ w1,
                                              const float* __restrict__ w2,
                                              const float* __restrict__ w3,
                                              u16* __restrict__ o0, u16* __restrict__ o1,
                                              u16* __restrict__ o2, u16* __restrict__ o3,
                                              const float* __restrict__ x,
                                              const float* __restrict__ g,
                                              const float* __restrict__ bb,
                                              u16* __restrict__ h) {
    __shared__ float tile[32][33];
    const int id = blockIdx.x;
    const int tx = threadIdx.x, ty = threadIdx.y;
    if (id < 6912) {
        const float* W;
        u16* WT;
        int K, N, loc;
        if (id < 1728) {            // w_attn 768x2304: 72x24 tiles
            W = w0; WT = o0; K = 768; N = 2304; loc = id;
        } else if (id < 2304) {     // w_proj 768x768
            W = w1; WT = o1; K = 768; N = 768; loc = id - 1728;
        } else if (id < 4608) {     // w_fc1 768x3072
            W = w2; WT = o2; K = 768; N = 3072; loc = id - 2304;
        } else {                    // w_fc2 3072x768
            W = w3; WT = o3; K = 3072; N = 768; loc = id - 4608;
        }
        const int nx = N >> 5;
        const int n0 = (loc % nx) * 32, k0 = (loc / nx) * 32;
#pragma unroll
        for (int i = 0; i < 4; ++i)
            tile[ty + i * 8][tx] = W[(size_t)(k0 + ty + i * 8) * N + n0 + tx];
        __syncthreads();
#pragma unroll
        for (int i = 0; i < 4; ++i)
            WT[(size_t)(n0 + ty + i * 8) * K + k0 + tx] = f2b(tile[tx][ty + i * 8]);
    } else {
        const int flat = ty * 32 + tx;
        const int lane = flat & 63, w = flat >> 6;
        const int row = (id - 6912) * 4 + w;
        const float4* xr = reinterpret_cast<const float4*>(x + (size_t)row * 768);
        float4 v[3];
        float s = 0.f, s2 = 0.f;
#pragma unroll
        for (int i = 0; i < 3; ++i) {
            v[i] = xr[i * 64 + lane];
            s += v[i].x + v[i].y + v[i].z + v[i].w;
            s2 += v[i].x * v[i].x + v[i].y * v[i].y + v[i].z * v[i].z + v[i].w * v[i].w;
        }
#pragma unroll
        for (int off = 1; off < 64; off <<= 1) {
            s += __shfl_xor(s, off);
            s2 += __shfl_xor(s2, off);
        }
        const float mu = s * (1.0f / 768.0f);
        const float rstd = rsqrtf(s2 * (1.0f / 768.0f) - mu * mu + 1e-5f);
#pragma unroll
        for (int i = 0; i < 3; ++i) {
            int col = i * 256 + lane * 4;
            u16x4 o;
            o[0] = f2b((v[i].x - mu) * rstd * g[col + 0] + bb[col + 0]);
            o[1] = f2b((v[i].y - mu) * rstd * g[col + 1] + bb[col + 1]);
            o[2] = f2b((v[i].z - mu) * rstd * g[col + 2] + bb[col + 2]);
            o[3] = f2b((v[i].w - mu) * rstd * g[col + 3] + bb[col + 3]);
            *reinterpret_cast<u16x4*>(h + (size_t)row * 768 + col) = o;
        }
    }
}

// ---------------- LayerNorm bf16-in: 1 wave per row of 768 -> bf16 ----------------
__global__ __launch_bounds__(256) void ln_b16(const u16* __restrict__ x,
                                              const float* __restrict__ g,
                                              const float* __restrict__ bb,
                                              u16* __restrict__ out) {
    const int lane = threadIdx.x & 63, w = threadIdx.x >> 6;
    const int row = blockIdx.x * 4 + w;
    const u16* xr = x + (size_t)row * 768;
    float v[12];
    float s = 0.f, s2 = 0.f;
#pragma unroll
    for (int i = 0; i < 3; ++i) {
        u16x4 u = *reinterpret_cast<const u16x4*>(xr + i * 256 + lane * 4);
#pragma unroll
        for (int jj = 0; jj < 4; ++jj) {
            float f = b2f(u[jj]);
            v[i * 4 + jj] = f;
            s += f;
            s2 += f * f;
        }
    }
#pragma unroll
    for (int off = 1; off < 64; off <<= 1) {
        s += __shfl_xor(s, off);
        s2 += __shfl_xor(s2, off);
    }
    const float mu = s * (1.0f / 768.0f);
    const float rstd = rsqrtf(s2 * (1.0f / 768.0f) - mu * mu + 1e-5f);
#pragma unroll
    for (int i = 0; i < 3; ++i) {
        int col = i * 256 + lane * 4;
        u16x4 o;
#pragma unroll
        for (int jj = 0; jj < 4; ++jj)
            o[jj] = f2b((v[i * 4 + jj] - mu) * rstd * g[col + jj] + bb[col + jj]);
        *reinterpret_cast<u16x4*>(out + (size_t)row * 768 + col) = o;
    }
}

// ------------- GEMM 128x128, BK=32, 4 waves, 3-slot rotation, 1 barrier/K-step ------
// K-loop unrolled in groups of 3; slot indices literal. MFAST=1: m-fastest XCD decode.
// RESIDT: 0 none, 1 fp32, 2 bf16. VOUT=1: V-region tiles (nBase>=1536) also scatter
// transposed u16x4 stores into vT (fuses the old vtrans kernel).
template <int ACT, int RESIDT, int OUTBF, int MFAST, int VOUT>
__global__ __launch_bounds__(256) void gemm_bt(const u16* __restrict__ A,
                                               const u16* __restrict__ BT,
                                               const float* __restrict__ bias,
                                               const void* __restrict__ resid,
                                               void* __restrict__ out,
                                               u16* __restrict__ vt,
                                               int M, int N, int K) {
    __shared__ u16 As[3 * 128 * 32];
    __shared__ u16 Bs[3 * 128 * 32];
    const int tid = threadIdx.x, lane = tid & 63;
    const int l15 = lane & 15, lg = lane >> 4;
    const int nx = gridDim.x;
    const int bid = blockIdx.y * nx + blockIdx.x;
    const int xcd = bid & 7;
    const int c = bid >> 3;
    int mBase, nBase;
    if (MFAST) {
        const int mh = gridDim.y >> 3;
        mBase = (xcd * mh + (c % mh)) * 128;
        nBase = (c / mh) * 128;
    } else {
        const int q = (nx * gridDim.y) >> 3;
        const int swz = xcd * q + c;
        mBase = (swz / nx) * 128;
        nBase = (swz % nx) * 128;
    }
    const int w = tid >> 6, wr = w >> 1, wc = w & 1;

    const int srow = tid >> 2;
    const int sg = ((tid & 3) ^ ((srow >> 1) & 3)) << 3;
    const u16* aCur = A + (size_t)(mBase + srow) * K + sg;
    const u16* bCur = BT + (size_t)(nBase + srow) * K + sg;
    const size_t half = (size_t)64 * K;
    const int dst0 = tid * 8, dst1 = (256 + tid) * 8;

    int offA[4], offB[4];
#pragma unroll
    for (int i = 0; i < 4; ++i) {
        int rA = wr * 64 + i * 16 + l15;
        offA[i] = rA * 32 + ((lg ^ ((rA >> 1) & 3)) << 3);
        int rB = wc * 64 + i * 16 + l15;
        offB[i] = rB * 32 + ((lg ^ ((rB >> 1) & 3)) << 3);
    }

    f32x4 acc[4][4] = {};
    const int nsteps = K >> 5;   // 24 or 96: divisible by 3

    {   // prologue: k=0 -> slot0, k=1 -> slot1
        async16(As + dst0, aCur);
        async16(As + dst1, aCur + half);
        async16(Bs + dst0, bCur);
        async16(Bs + dst1, bCur + half);
        async16(As + 4096 + dst0, aCur + 32);
        async16(As + 4096 + dst1, aCur + half + 32);
        async16(Bs + 4096 + dst0, bCur + 32);
        async16(Bs + 4096 + dst1, bCur + half + 32);
    }

    auto step = [&](int slot, int kk, int stageOfs) {
        if (kk + 1 < nsteps) {
            asm volatile("s_waitcnt vmcnt(4)" ::: "memory");
        } else {
            asm volatile("s_waitcnt vmcnt(0)" ::: "memory");
        }
        __builtin_amdgcn_s_barrier();
        asm volatile("" ::: "memory");
        if (kk + 2 < nsteps) {
            int ns = slot + 2;
            if (ns >= 3) ns -= 3;
            u16* sa = As + ns * 4096;
            u16* sb = Bs + ns * 4096;
            async16(sa + dst0, aCur + stageOfs);
            async16(sa + dst1, aCur + half + stageOfs);
            async16(sb + dst0, bCur + stageOfs);
            async16(sb + dst1, bCur + half + stageOfs);
        }
        const u16* sA = As + slot * 4096;
        const u16* sB = Bs + slot * 4096;
        bf16x8 af[4], bfr[4];
#pragma unroll
        for (int mi = 0; mi < 4; ++mi) af[mi] = load8(sA + offA[mi]);
#pragma unroll
        for (int ni = 0; ni < 4; ++ni) bfr[ni] = load8(sB + offB[ni]);
        __builtin_amdgcn_s_setprio(1);
#pragma unroll
        for (int mi = 0; mi < 4; ++mi)
#pragma unroll
            for (int ni = 0; ni < 4; ++ni)
                acc[mi][ni] = __builtin_amdgcn_mfma_f32_16x16x32_bf16(
                    af[mi], bfr[ni], acc[mi][ni], 0, 0, 0);
        __builtin_amdgcn_s_setprio(0);
        asm volatile("" ::: "memory");
    };

    for (int kk = 0; kk < nsteps; kk += 3) {
        step(0, kk, 64);
        step(1, kk + 1, 96);
        step(2, kk + 2, 128);
        aCur += 96;
        bCur += 96;
    }

    const bool vtile = VOUT && (nBase >= 1536);
#pragma unroll
    for (int mi = 0; mi < 4; ++mi) {
#pragma unroll
        for (int ni = 0; ni < 4; ++ni) {
            const int row0 = mBase + wr * 64 + mi * 16 + lg * 4;
            const int col = nBase + wc * 64 + ni * 16 + l15;
            const float bv = bias[col];
            u16x4 cv;
#pragma unroll
            for (int r = 0; r < 4; ++r) {
                float v = acc[mi][ni][r] + bv;
                if (ACT == 1) v = gelu_t(v);
                size_t off = (size_t)(row0 + r) * N + col;
                if (RESIDT == 1) v += ((const float*)resid)[off];
                if (RESIDT == 2) v += b2f(((const u16*)resid)[off]);
                if (OUTBF) {
                    u16 hv = f2b(v);
                    cv[r] = hv;
                    ((u16*)out)[off] = hv;
                } else {
                    ((float*)out)[off] = v;
                }
            }
            if (vtile) {
                // transposed V copy: 4 consecutive t-values at fixed d
                const int dg = col - 1536;                    // 0..767
                const int bh = (row0 >> 10) * 12 + (dg >> 6); // batch*12 + head
                const int d = dg & 63;
                const int t0 = row0 & 1023;
                *reinterpret_cast<u16x4*>(vt + (size_t)(bh * 64 + d) * 1024 + t0) = cv;
            }
        }
    }
}

// ------------- causal flash attention: swapped QK^T + in-register softmax -------------
__global__ __launch_bounds__(256, 3) void attn_k(const u16* __restrict__ qkv,
                                                 const u16* __restrict__ vT,
                                                 u16* __restrict__ y) {
    __shared__ u16 Ks[2][64 * 64];
    __shared__ u16 Vs[2][64 * 64];
    __shared__ u16 Ps[4][2][16 * 64];
    const int tid = threadIdx.x, lane = tid & 63, w = tid >> 6;
    const int bid = blockIdx.x;
    const uint32_t permPk = 2u | (7u << 3) | (1u << 6) | (4u << 9) | (6u << 12) |
                            (0u << 15) | (5u << 18) | (3u << 21);
    const int qt = (permPk >> (((bid + (bid >> 8)) & 7) * 3)) & 7;
    const int bh = ((bid >> 8) << 5) + ((bid & 255) >> 3);
    const int b = bh / 12, hd = bh % 12;
    const int l15 = lane & 15, lg = lane >> 4;
    const int r0 = qt * 128 + w * 32;

    const float qscale = 0.125f * 1.4426950408889634f;
    bf16x8 qf[2][2];
#pragma unroll
    for (int m = 0; m < 2; ++m) {
        const u16* qb = qkv + (size_t)(b * 1024 + r0 + m * 16 + l15) * 2304 + hd * 64;
#pragma unroll
        for (int ks = 0; ks < 2; ++ks) {
            u16x8 u = *reinterpret_cast<const u16x8*>(qb + ks * 32 + lg * 8);
            u16x8 o;
#pragma unroll
            for (int jj = 0; jj < 8; ++jj) o[jj] = f2b(b2f(u[jj]) * qscale);
            qf[m][ks] = __builtin_bit_cast(bf16x8, o);
        }
    }

    const int srow = tid >> 3;
    const int ssc = ((tid & 7) ^ (srow & 7)) << 3;
    const u16* kSrc = qkv + (size_t)(b * 1024 + srow) * 2304 + 768 + hd * 64 + ssc;
    const u16* vSrc = vT + (size_t)(bh * 64 + srow) * 1024 + ssc;
    const int dst0 = tid * 8, dst1 = (256 + tid) * 8;

    auto stage = [&](int buf, int j) {
        const size_t kOff = (size_t)j * 64 * 2304;
        const int vOff = j * 64;
        async16(Ks[buf] + dst0, kSrc + kOff);
        async16(Ks[buf] + dst1, kSrc + kOff + (size_t)32 * 2304);
        async16(Vs[buf] + dst0, vSrc + vOff);
        async16(Vs[buf] + dst1, vSrc + vOff + 32 * 1024);
    };

    f32x4 oacc[2][4] = {};
    float mrow[2] = {-1e30f, -1e30f};
    float lrow[2] = {0.f, 0.f};

    const int jd = (r0 + 31) >> 6;
    const int jmax = qt * 2 + 1;

    stage(0, 0);
    for (int j = 0; j <= jmax; ++j) {
        const int cur = j & 1;
        if (j < jmax) {
            stage(cur ^ 1, j + 1);
            asm volatile("s_waitcnt vmcnt(4)" ::: "memory");
        } else {
            asm volatile("s_waitcnt vmcnt(0)" ::: "memory");
        }
        __builtin_amdgcn_s_barrier();
        asm volatile("" ::: "memory");

        if (j <= jd) {
            const bool diag = (j == jd);
            const u16* Kc = Ks[cur];
            const u16* Vc = Vs[cur];
            f32x4 s[2][4] = {};
            __builtin_amdgcn_s_setprio(1);
#pragma unroll
            for (int ks = 0; ks < 2; ++ks) {
                bf16x8 kf[4];
#pragma unroll
                for (int ni = 0; ni < 4; ++ni) {
                    int key = ni * 16 + l15;
                    kf[ni] = load8(Kc + key * 64 + (((ks * 4 + lg) ^ (key & 7)) << 3));
                }
#pragma unroll
                for (int ni = 0; ni < 4; ++ni) {
                    s[0][ni] = __builtin_amdgcn_mfma_f32_16x16x32_bf16(
                        kf[ni], qf[0][ks], s[0][ni], 0, 0, 0);
                    s[1][ni] = __builtin_amdgcn_mfma_f32_16x16x32_bf16(
                        kf[ni], qf[1][ks], s[1][ni], 0, 0, 0);
                }
            }
            __builtin_amdgcn_s_setprio(0);

#pragma unroll
            for (int m = 0; m < 2; ++m) {
                if (diag) {
                    const int qrow = r0 + m * 16 + l15;
#pragma unroll
                    for (int ni = 0; ni < 4; ++ni) {
                        int key = j * 64 + ni * 16 + lg * 4;
#pragma unroll
                        for (int r = 0; r < 4; ++r)
                            if (key + r > qrow) s[m][ni][r] = -1e30f;
                    }
                }
                float pmax = -1e30f;
#pragma unroll
                for (int ni = 0; ni < 4; ++ni)
#pragma unroll
                    for (int r = 0; r < 4; ++r) pmax = fmaxf(pmax, s[m][ni][r]);
                pmax = fmaxf(pmax, __shfl_xor(pmax, 16));
                pmax = fmaxf(pmax, __shfl_xor(pmax, 32));

                if (!__all(pmax <= mrow[m] + 8.0f)) {
                    float mnew = fmaxf(mrow[m], pmax);
                    float scal = exp2f(mrow[m] - mnew);
                    mrow[m] = mnew;
                    lrow[m] *= scal;
#pragma unroll
                    for (int r = 0; r < 4; ++r) {
                        float sr = __shfl(scal, lg * 4 + r);
#pragma unroll
                        for (int ni = 0; ni < 4; ++ni) oacc[m][ni][r] *= sr;
                    }
                }
                float psum = 0.f;
#pragma unroll
                for (int ni = 0; ni < 4; ++ni) {
                    u16x4 pk;
#pragma unroll
                    for (int r = 0; r < 4; ++r) {
                        float pv = exp2f(s[m][ni][r] - mrow[m]);
                        psum += pv;
                        pk[r] = f2b(pv);
                    }
                    *reinterpret_cast<u16x4*>(
                        &Ps[w][m][l15 * 64 + ((ni * 16 + lg * 4) ^ ((l15 & 7) << 3))]) =
                        pk;
                }
                psum += __shfl_xor(psum, 16);
                psum += __shfl_xor(psum, 32);
                lrow[m] += psum;
            }

            __builtin_amdgcn_s_setprio(1);
#pragma unroll
            for (int ks = 0; ks < 2; ++ks) {
                bf16x8 pf0 = load8(
                    &Ps[w][0][l15 * 64 + ((ks * 32 + lg * 8) ^ ((l15 & 7) << 3))]);
                bf16x8 pf1 = load8(
                    &Ps[w][1][l15 * 64 + ((ks * 32 + lg * 8) ^ ((l15 & 7) << 3))]);
                bf16x8 vf[4];
#pragma unroll
                for (int ni = 0; ni < 4; ++ni) {
                    int d = ni * 16 + l15;
                    vf[ni] = load8(Vc + d * 64 + (((ks * 4 + lg) ^ (d & 7)) << 3));
                }
#pragma unroll
                for (int ni = 0; ni < 4; ++ni) {
                    oacc[0][ni] = __builtin_amdgcn_mfma_f32_16x16x32_bf16(
                        pf0, vf[ni], oacc[0][ni], 0, 0, 0);
                    oacc[1][ni] = __builtin_amdgcn_mfma_f32_16x16x32_bf16(
                        pf1, vf[ni], oacc[1][ni], 0, 0, 0);
                }
            }
            __builtin_amdgcn_s_setprio(0);
        }
        asm volatile("" ::: "memory");
        __builtin_amdgcn_s_barrier();
        asm volatile("" ::: "memory");
    }

#pragma unroll
    for (int m = 0; m < 2; ++m) {
#pragma unroll
        for (int r = 0; r < 4; ++r) {
            float rl = 1.0f / __shfl(lrow[m], lg * 4 + r);
            int row = r0 + m * 16 + lg * 4 + r;
#pragma unroll
            for (int ni = 0; ni < 4; ++ni) {
                int col = hd * 64 + ni * 16 + l15;
                y[(size_t)(b * 1024 + row) * 768 + col] = f2b(oacc[m][ni][r] * rl);
            }
        }
    }
}

extern "C" void kernel_launch(void* const* d_in, const int* in_sizes, int n_in,
                              void* d_out, int out_size, void* d_ws, size_t ws_size,
                              hipStream_t stream) {
    const float* x      = (const float*)d_in[0];
    const float* ln1_g  = (const float*)d_in[1];
    const float* ln1_b  = (const float*)d_in[2];
    const float* w_attn = (const float*)d_in[3];
    const float* b_attn = (const float*)d_in[4];
    const float* w_proj = (const float*)d_in[5];
    const float* b_proj = (const float*)d_in[6];
    const float* ln2_g  = (const float*)d_in[7];
    const float* ln2_b  = (const float*)d_in[8];
    const float* w_fc1  = (const float*)d_in[9];
    const float* b_fc1  = (const float*)d_in[10];
    const float* w_fc2  = (const float*)d_in[11];
    const float* b_fc2  = (const float*)d_in[12];
    float* out = (float*)d_out;

    char* p = (char*)d_ws;
    auto take = [&](size_t n) {
        char* r = p;
        p += (n + 255) & ~(size_t)255;
        return r;
    };
    u16* wT_attn = (u16*)take((size_t)2304 * 768 * 2);
    u16* wT_proj = (u16*)take((size_t)768 * 768 * 2);
    u16* wT_fc1  = (u16*)take((size_t)3072 * 768 * 2);
    u16* wT_fc2  = (u16*)take((size_t)768 * 3072 * 2);
    u16* h       = (u16*)take((size_t)8192 * 768 * 2);   // h1 / h2 (aliased)
    u16* bufA    = (u16*)take((size_t)50331648);         // qkv+vT, later g1
    u16* yb      = (u16*)take((size_t)8192 * 768 * 2);
    u16* x1b     = (u16*)take((size_t)8192 * 768 * 2);   // residual stream, bf16
    u16* qkv = bufA;
    u16* vT  = bufA + (size_t)8192 * 2304;
    u16* g1  = bufA;

    const dim3 tb(32, 8);
    // fused: weight transposes + ln1
    prep_k<<<8960, tb, 0, stream>>>(w_attn, w_proj, w_fc1, w_fc2,
                                    wT_attn, wT_proj, wT_fc1, wT_fc2,
                                    x, ln1_g, ln1_b, h);
    // qkv = h @ w_attn + b_attn -> bf16, with fused V-transpose into vT
    gemm_bt<0, 0, 1, 1, 1><<<dim3(18, 64), 256, 0, stream>>>(
        h, wT_attn, b_attn, nullptr, qkv, vT, 8192, 2304, 768);
    // attention
    attn_k<<<768, 256, 0, stream>>>(qkv, vT, yb);
    // x1b = bf16(x + y @ w_proj + b_proj)
    gemm_bt<0, 1, 1, 1, 0><<<dim3(6, 64), 256, 0, stream>>>(
        yb, wT_proj, b_proj, x, x1b, nullptr, 8192, 768, 768);
    // ln2 (bf16 input)
    ln_b16<<<2048, 256, 0, stream>>>(x1b, ln2_g, ln2_b, h);
    // g1 = gelu(h @ w_fc1 + b_fc1) -> bf16
    gemm_bt<1, 0, 1, 1, 0><<<dim3(24, 64), 256, 0, stream>>>(
        h, wT_fc1, b_fc1, nullptr, g1, nullptr, 8192, 3072, 768);
    // out = x1b + g1 @ w_fc2 + b_fc2  (fp32 out, bf16 resid; n-fastest)
    gemm_bt<0, 2, 0, 0, 0><<<dim3(6, 64), 256, 0, stream>>>(
        g1, wT_fc2, b_fc2, x1b, out, nullptr, 8192, 768, 3072);
}